// Round 1
// 564.422 us; speedup vs baseline: 1.0179x; 1.0179x over previous
//
#include <hip/hip_runtime.h>

#define B_   16
#define C_   384
#define CR_  96
#define BC_  (B_ * C_)     // 6144 planes
#define HW_  12544         // 112*112
#define HW4_ 3136          // HW/4, divisible by 64

typedef float f4v __attribute__((ext_vector_type(4)));

// ---------------------------------------------------------------------------
// Kernel 1: global average pool. One block per (b,c) plane, ASCENDING order.
// Regular (caching) loads on purpose: the residue this leaves in the 256 MB
// Infinity Cache (the tail of x) is harvested by the reversed gate kernel.
// ---------------------------------------------------------------------------
__global__ __launch_bounds__(256) void se_pool(const float* __restrict__ x,
                                               float* __restrict__ s) {
    const int bc = blockIdx.x;
    const float4* __restrict__ p = (const float4*)(x + (size_t)bc * HW_);

    float sum = 0.f;
    for (int i = threadIdx.x; i < HW4_; i += 256) {
        float4 v = p[i];
        sum += (v.x + v.y) + (v.z + v.w);
    }
    // wave (64-lane) reduction
    #pragma unroll
    for (int off = 32; off > 0; off >>= 1)
        sum += __shfl_down(sum, off, 64);

    __shared__ float wsum[4];
    const int lane = threadIdx.x & 63;
    const int wid  = threadIdx.x >> 6;
    if (lane == 0) wsum[wid] = sum;
    __syncthreads();
    if (threadIdx.x == 0) {
        float t = (wsum[0] + wsum[1]) + (wsum[2] + wsum[3]);
        s[bc] = t * (1.0f / (float)HW_);
    }
}

// ---------------------------------------------------------------------------
// Kernel 2: fc1+ReLU, fc2+bias, hardsigmoid. One block per batch element.
// float4 weight loads: each thread's weight row is contiguous, so 4x fewer
// load instructions on this latency-bound kernel. LDS reads are uniform
// (broadcast, conflict-free).
// ---------------------------------------------------------------------------
__global__ __launch_bounds__(384) void se_fc(const float* __restrict__ s,
                                             const float* __restrict__ w1,
                                             const float* __restrict__ b1,
                                             const float* __restrict__ w2,
                                             const float* __restrict__ b2,
                                             float* __restrict__ scale) {
    const int b = blockIdx.x;
    const int t = threadIdx.x;

    __shared__ float sl[C_];
    __shared__ float hid[CR_];

    if (t < C_) sl[t] = s[b * C_ + t];
    __syncthreads();

    if (t < CR_) {
        float acc = b1[t];
        const float4* __restrict__ wr = (const float4*)(w1 + (size_t)t * C_);
        const float4* __restrict__ sv = (const float4*)sl;
        #pragma unroll 8
        for (int k = 0; k < C_ / 4; ++k) {
            float4 w = wr[k];
            float4 v = sv[k];
            acc = fmaf(v.x, w.x, acc);
            acc = fmaf(v.y, w.y, acc);
            acc = fmaf(v.z, w.z, acc);
            acc = fmaf(v.w, w.w, acc);
        }
        hid[t] = fmaxf(acc, 0.f);
    }
    __syncthreads();

    {
        float acc = b2[t];
        const float4* __restrict__ wr = (const float4*)(w2 + (size_t)t * CR_);
        const float4* __restrict__ hv = (const float4*)hid;
        #pragma unroll 6
        for (int k = 0; k < CR_ / 4; ++k) {
            float4 w = wr[k];
            float4 v = hv[k];
            acc = fmaf(v.x, w.x, acc);
            acc = fmaf(v.y, w.y, acc);
            acc = fmaf(v.z, w.z, acc);
            acc = fmaf(v.w, w.w, acc);
        }
        float g = acc * (1.0f / 6.0f) + 0.5f;          // hardsigmoid
        g = fminf(fmaxf(g, 0.f), 1.f);
        scale[b * C_ + t] = g;
    }
}

// ---------------------------------------------------------------------------
// Kernel 3: out[b,c,:,:] = x[b,c,:,:] * scale[b,c].
// One block per plane, DESCENDING plane order: the first ~250 MB read is the
// x-tail that se_pool just left in the Infinity Cache. Non-temporal loads
// (read-once: don't re-allocate on miss) and non-temporal stores (write-once:
// don't evict the x residue with the out stream). scale is wave-uniform.
// ---------------------------------------------------------------------------
__global__ __launch_bounds__(256) void se_gate(const float* __restrict__ x,
                                               const float* __restrict__ scale,
                                               float* __restrict__ out) {
    const int plane = (BC_ - 1) - (int)blockIdx.x;    // reversed traversal
    const float g = scale[plane];

    const f4v* __restrict__ xp = (const f4v*)(x + (size_t)plane * HW_);
    f4v*       __restrict__ op = (f4v*)(out + (size_t)plane * HW_);

    for (int i = threadIdx.x; i < HW4_; i += 256) {
        f4v v = __builtin_nontemporal_load(xp + i);
        v = v * g;
        __builtin_nontemporal_store(v, op + i);
    }
}

// ---------------------------------------------------------------------------
extern "C" void kernel_launch(void* const* d_in, const int* in_sizes, int n_in,
                              void* d_out, int out_size, void* d_ws, size_t ws_size,
                              hipStream_t stream) {
    const float* x  = (const float*)d_in[0];
    const float* w1 = (const float*)d_in[1];
    const float* b1 = (const float*)d_in[2];
    const float* w2 = (const float*)d_in[3];
    const float* b2 = (const float*)d_in[4];
    float* out = (float*)d_out;

    float* s_buf     = (float*)d_ws;                 // B*C floats
    float* scale_buf = s_buf + B_ * C_;              // B*C floats

    // 1) pool: 6144 planes, ascending (seeds L3 with the tail of x)
    se_pool<<<BC_, 256, 0, stream>>>(x, s_buf);

    // 2) fc chain: 16 blocks
    se_fc<<<B_, 384, 0, stream>>>(s_buf, w1, b1, w2, b2, scale_buf);

    // 3) gate: 6144 planes, descending (harvests the L3 x-tail)
    se_gate<<<BC_, 256, 0, stream>>>(x, scale_buf, out);
}